// Round 4
// baseline (469.628 us; speedup 1.0000x reference)
//
#include <hip/hip_runtime.h>
#include <hip/hip_bf16.h>

namespace {

constexpr int Bn   = 32;
constexpr int IMG  = 48;
constexpr int Dm   = 384;
constexpr int NHn  = 8;
constexpr int WSn  = 6;
constexpr int NWn  = 64;          // 8x8 windows
constexpr int Mn   = Bn * NWn;    // 2048 windows
constexpr int Vn   = 36;          // tokens per window
constexpr int ROWS = Mn * Vn;     // 73728 token rows
constexpr int K3   = 3 * Dm;      // 1152
constexpr int QKW  = 768;         // q|k packed row width
constexpr int XSS  = 392;         // Xs stride: 784B pitch -> 2-way bank alias (free)
constexpr float SCALE = 0.14433756729740643f;  // 48^-0.5

using short8 = __attribute__((ext_vector_type(8))) short;
using f32x4  = __attribute__((ext_vector_type(4))) float;

__device__ __forceinline__ float bf2f(unsigned short u) {
    return __uint_as_float(((unsigned)u) << 16);
}
__device__ __forceinline__ unsigned short f2bf(float f) {
    unsigned u = __float_as_uint(f);
    u += 0x7FFFu + ((u >> 16) & 1u);   // RNE
    return (unsigned short)(u >> 16);
}

// async global->LDS, 16B per lane; LDS dest = wave-uniform base + lane*16
__device__ __forceinline__ void gl_lds16(const unsigned short* g, unsigned short* l) {
    __builtin_amdgcn_global_load_lds(
        (const __attribute__((address_space(1))) unsigned int*)g,
        (__attribute__((address_space(3))) unsigned int*)l, 16, 0, 0);
}

// 16B load from only-8B-aligned address (vt rows are 72B apart)
union U8 { short8 v; uint2 u[2]; };
__device__ __forceinline__ short8 ld8B(const unsigned short* p) {
    U8 r; r.u[0] = *(const uint2*)p; r.u[1] = *(const uint2*)(p + 4); return r.v;
}

// row -> gathered source base (roll(-3) + window partition), in elements
__device__ __forceinline__ int gather_base(int row) {
    int m = row / Vn, v = row - m * Vn;
    int b = m >> 6, w = m & 63;
    int wh = w >> 3, ww = w & 7;
    int gh = wh * WSn + v / WSn;
    int gw = ww * WSn + v % WSn;
    int fi = (gh + 3) % IMG;
    int fj = (gw + 3) % IMG;
    return ((b * IMG + fi) * IMG + fj) * Dm;
}

// region id of token t in window (wh, ww)
__device__ __forceinline__ int region_id(int t, int wh, int ww) {
    int hi = (wh == 7) ? ((t / 6) < 3) : 1;
    int lo = (ww == 7) ? ((t % 6) < 3) : 1;
    return (hi << 1) | lo;
}

// ---------------------------------------------------------------------------
// prep_w: wqT[n][k] = bf16(wq[k][n]);  wpT[n][k] = bf16(wp[k][n])
// ---------------------------------------------------------------------------
__global__ __launch_bounds__(256)
void prep_w(const float* __restrict__ wq, const float* __restrict__ wp,
            unsigned short* __restrict__ wqT, unsigned short* __restrict__ wpT)
{
    int idx = blockIdx.x * 256 + threadIdx.x;
    if (idx < K3 * Dm) {
        int n = idx / Dm, k = idx - n * Dm;
        wqT[idx] = f2bf(wq[(size_t)k * K3 + n]);
    } else {
        int i2 = idx - K3 * Dm;
        if (i2 < Dm * Dm) {
            int n = i2 / Dm, k = i2 - n * Dm;
            wpT[i2] = f2bf(wp[(size_t)k * Dm + n]);
        }
    }
}

// ---------------------------------------------------------------------------
// qkv_fused: A-resident GEMM. Block = 64 token rows; gather+cvt x into LDS
// once; loop 9 n-tiles x (BK=64 as two 32-wide buffers) streaming weights via
// global_load_lds. Epilogue: q|k -> qkb rows, v -> vt transposed.
// ---------------------------------------------------------------------------
__global__ __launch_bounds__(256)
void qkv_fused(const float* __restrict__ x,
               const unsigned short* __restrict__ wqT,
               const float* __restrict__ bq,
               unsigned short* __restrict__ qkb,
               unsigned short* __restrict__ vt)
{
    __shared__ __align__(16) unsigned short Xs[64 * XSS];
    __shared__ __align__(16) unsigned short Bs0[128 * 32];
    __shared__ __align__(16) unsigned short Bs1[128 * 32];

    const int tid  = threadIdx.x;
    const int wave = tid >> 6, lane = tid & 63;
    const int quad = lane >> 4, l15 = lane & 15;
    const int rowA0 = blockIdx.x * 64;

    // ---- stage A: gather + fp32->bf16, once per block ----
    {
        const int row = tid >> 2, q4 = tid & 3;
        const float* src = x + (size_t)gather_base(rowA0 + row) + q4 * 96;
        unsigned short* dst = Xs + row * XSS + q4 * 96;
#pragma unroll
        for (int c = 0; c < 12; c++) {
            float4 a = *(const float4*)(src + c * 8);
            float4 b = *(const float4*)(src + c * 8 + 4);
            short8 o;
            o[0] = (short)f2bf(a.x); o[1] = (short)f2bf(a.y);
            o[2] = (short)f2bf(a.z); o[3] = (short)f2bf(a.w);
            o[4] = (short)f2bf(b.x); o[5] = (short)f2bf(b.y);
            o[6] = (short)f2bf(b.z); o[7] = (short)f2bf(b.w);
            *(short8*)(dst + c * 8) = o;
        }
    }

    const int r_in = lane >> 2;          // 0..15
    const int kc   = (lane & 3) * 8;     // 8-elem chunk within 32
    const int wm   = wave >> 1, wn = wave & 1;
    unsigned short* lB0a = &Bs0[(wave * 32) * 32];
    unsigned short* lB0b = &Bs0[(wave * 32 + 16) * 32];
    unsigned short* lB1a = &Bs1[(wave * 32) * 32];
    unsigned short* lB1b = &Bs1[(wave * 32 + 16) * 32];

    for (int nT = 0; nT < 9; nT++) {
        const unsigned short* gB = wqT + (size_t)(nT * 128 + wave * 32 + r_in) * Dm + kc;
        f32x4 acc[2][4];
#pragma unroll
        for (int i = 0; i < 2; i++)
#pragma unroll
            for (int j = 0; j < 4; j++) acc[i][j] = (f32x4){0.f, 0.f, 0.f, 0.f};

        for (int k0 = 0; k0 < Dm; k0 += 64) {
            __syncthreads();
            gl_lds16(gB + k0,            lB0a);
            gl_lds16(gB + 16 * Dm + k0,  lB0b);
            gl_lds16(gB + k0 + 32,       lB1a);
            gl_lds16(gB + 16 * Dm + k0 + 32, lB1b);
            __syncthreads();
            short8 af0[2], af1[2], bf0[4], bf1[4];
#pragma unroll
            for (int i = 0; i < 2; i++) {
                const unsigned short* ar = &Xs[(wm * 32 + i * 16 + l15) * XSS + k0 + quad * 8];
                af0[i] = *(const short8*)ar;
                af1[i] = *(const short8*)(ar + 32);
            }
#pragma unroll
            for (int j = 0; j < 4; j++) {
                bf0[j] = *(const short8*)&Bs0[(wn * 64 + j * 16 + l15) * 32 + quad * 8];
                bf1[j] = *(const short8*)&Bs1[(wn * 64 + j * 16 + l15) * 32 + quad * 8];
            }
#pragma unroll
            for (int i = 0; i < 2; i++)
#pragma unroll
                for (int j = 0; j < 4; j++) {
                    acc[i][j] = __builtin_amdgcn_mfma_f32_16x16x32_bf16(af0[i], bf0[j], acc[i][j], 0, 0, 0);
                    acc[i][j] = __builtin_amdgcn_mfma_f32_16x16x32_bf16(af1[i], bf1[j], acc[i][j], 0, 0, 0);
                }
        }

        // ---- epilogue for this n-tile ----
        if (nT < 6) {
#pragma unroll
            for (int j = 0; j < 4; j++) {
                int col = nT * 128 + wn * 64 + j * 16 + l15;
                float b = bq[col];
#pragma unroll
                for (int i = 0; i < 2; i++)
#pragma unroll
                    for (int r = 0; r < 4; r++) {
                        int row = rowA0 + wm * 32 + i * 16 + quad * 4 + r;
                        qkb[(size_t)row * QKW + col] = f2bf(acc[i][j][r] + b);
                    }
            }
        } else {
#pragma unroll
            for (int j = 0; j < 4; j++) {
                int col = nT * 128 + wn * 64 + j * 16 + l15;
                float b = bq[col];
                int c  = col - QKW;
                int hh = c / 48, dd = c - hh * 48;
#pragma unroll
                for (int i = 0; i < 2; i++)
#pragma unroll
                    for (int r = 0; r < 4; r++) {
                        int row = rowA0 + wm * 32 + i * 16 + quad * 4 + r;
                        int mm = row / 36, vv = row - mm * 36;
                        vt[((size_t)(mm * 8 + hh) * 48 + dd) * 36 + vv] = f2bf(acc[i][j][r] + b);
                    }
            }
        }
    }
}

// ---------------------------------------------------------------------------
// attn_mfma: one wave per (window m, head h); MFMA QK^T / PV, K padded to 64
// with A-side-only zeroing; P round-trips LDS (C-layout -> A-layout).
// ---------------------------------------------------------------------------
__global__ __launch_bounds__(256)
void attn_mfma(const unsigned short* __restrict__ qk,
               const unsigned short* __restrict__ vt,
               unsigned short* __restrict__ att)
{
    __shared__ __align__(16) unsigned short Pl[4][48 * 56];

    const int tid  = threadIdx.x;
    const int wave = tid >> 6, lane = tid & 63;
    const int quad = lane >> 4, l15 = lane & 15;
    const int W = blockIdx.x * 4 + wave;
    const int m = W >> 3, h = W & 7;
    const int w = m & 63, wh = w >> 3, ww = w & 7;

    const short8 zf = {0, 0, 0, 0, 0, 0, 0, 0};

    const unsigned short* qbase = qk + (size_t)(m * 36) * QKW + h * 48;
    short8 qf[3][2], kf[3][2];
#pragma unroll
    for (int t = 0; t < 3; t++) {
        const unsigned short* qr = qbase + (size_t)(t * 16 + l15) * QKW;
        qf[t][0] = *(const short8*)(qr + quad * 8);
        qf[t][1] = (quad < 2) ? *(const short8*)(qr + 32 + quad * 8) : zf;  // k>=48 zero (A side)
        const unsigned short* kr = qbase + 384 + (size_t)(t * 16 + l15) * QKW;
        kf[t][0] = *(const short8*)(kr + quad * 8);
        kf[t][1] = *(const short8*)(kr + 32 + quad * 8);                    // garbage ok (B side)
    }

    f32x4 acc[3][3];
#pragma unroll
    for (int i = 0; i < 3; i++)
#pragma unroll
        for (int j = 0; j < 3; j++) acc[i][j] = (f32x4){0.f, 0.f, 0.f, 0.f};
#pragma unroll
    for (int i = 0; i < 3; i++)
#pragma unroll
        for (int j = 0; j < 3; j++) {
            acc[i][j] = __builtin_amdgcn_mfma_f32_16x16x32_bf16(qf[i][0], kf[j][0], acc[i][j], 0, 0, 0);
            acc[i][j] = __builtin_amdgcn_mfma_f32_16x16x32_bf16(qf[i][1], kf[j][1], acc[i][j], 0, 0, 0);
        }

    // mask + exp + row-sum (butterfly across the 16-lane col group)
#pragma unroll
    for (int i = 0; i < 3; i++) {
        float rs[4] = {0.f, 0.f, 0.f, 0.f};
#pragma unroll
        for (int j = 0; j < 3; j++) {
            int C = j * 16 + l15;
            int idc = region_id(C, wh, ww);
#pragma unroll
            for (int r = 0; r < 4; r++) {
                int R = i * 16 + quad * 4 + r;
                int idr = region_id(R, wh, ww);
                float s = acc[i][j][r] * SCALE;
                s = (C >= 36 || idr != idc) ? -1e30f : fminf(s, 30.f);
                float e = __expf(s);
                acc[i][j][r] = e;
                rs[r] += e;
            }
        }
#pragma unroll
        for (int r = 0; r < 4; r++) {
#pragma unroll
            for (int d = 1; d < 16; d <<= 1) rs[r] += __shfl_xor(rs[r], d, 16);
            rs[r] = 1.f / rs[r];
        }
#pragma unroll
        for (int j = 0; j < 3; j++)
#pragma unroll
            for (int r = 0; r < 4; r++) {
                int R = i * 16 + quad * 4 + r;
                int C = j * 16 + l15;
                Pl[wave][R * 56 + C] = f2bf(acc[i][j][r] * rs[r]);
            }
    }
    __syncthreads();

    short8 pf[3][2], vf[3][2];
#pragma unroll
    for (int t = 0; t < 3; t++) {
        const unsigned short* pr = &Pl[wave][(t * 16 + l15) * 56];
        pf[t][0] = *(const short8*)(pr + quad * 8);
        pf[t][1] = (quad < 2) ? *(const short8*)(pr + 32 + quad * 8) : zf;
        const unsigned short* vr = vt + ((size_t)(m * 8 + h) * 48 + t * 16 + l15) * 36;
        vf[t][0] = ld8B(vr + quad * 8);
        vf[t][1] = ld8B(vr + 32 + quad * 8);    // tokens>=36 garbage, killed by P=0
    }
    f32x4 oacc[3][3];
#pragma unroll
    for (int i = 0; i < 3; i++)
#pragma unroll
        for (int j = 0; j < 3; j++) oacc[i][j] = (f32x4){0.f, 0.f, 0.f, 0.f};
#pragma unroll
    for (int i = 0; i < 3; i++)
#pragma unroll
        for (int j = 0; j < 3; j++) {
            oacc[i][j] = __builtin_amdgcn_mfma_f32_16x16x32_bf16(pf[i][0], vf[j][0], oacc[i][j], 0, 0, 0);
            oacc[i][j] = __builtin_amdgcn_mfma_f32_16x16x32_bf16(pf[i][1], vf[j][1], oacc[i][j], 0, 0, 0);
        }

#pragma unroll
    for (int i = 0; i < 3; i++)
#pragma unroll
        for (int r = 0; r < 4; r++) {
            int R = i * 16 + quad * 4 + r;
            if (R < 36) {
#pragma unroll
                for (int j = 0; j < 3; j++)
                    att[((size_t)m * 36 + R) * Dm + h * 48 + j * 16 + l15] = f2bf(oacc[i][j][r]);
            }
        }
}

// ---------------------------------------------------------------------------
// proj_fused: A-resident proj GEMM. Block = 64 att rows in LDS; 3 n-tiles x
// BK=64 weight streaming; scatter epilogue (window-reverse + roll(+3)).
// ---------------------------------------------------------------------------
__global__ __launch_bounds__(256)
void proj_fused(const unsigned short* __restrict__ att,
                const unsigned short* __restrict__ wpT,
                const float* __restrict__ bp,
                float* __restrict__ out)
{
    __shared__ __align__(16) unsigned short Xs[64 * XSS];
    __shared__ __align__(16) unsigned short Bs0[128 * 32];
    __shared__ __align__(16) unsigned short Bs1[128 * 32];
    __shared__ int rowOut[64];

    const int tid  = threadIdx.x;
    const int wave = tid >> 6, lane = tid & 63;
    const int quad = lane >> 4, l15 = lane & 15;
    const int rowA0 = blockIdx.x * 64;

    if (tid < 64) rowOut[tid] = gather_base(rowA0 + tid);

    {
        const int row = tid >> 2, q4 = tid & 3;
        const unsigned short* src = att + (size_t)(rowA0 + row) * Dm + q4 * 96;
        unsigned short* dst = Xs + row * XSS + q4 * 96;
#pragma unroll
        for (int c = 0; c < 12; c++)
            *(short8*)(dst + c * 8) = *(const short8*)(src + c * 8);
    }

    const int r_in = lane >> 2;
    const int kc   = (lane & 3) * 8;
    const int wm   = wave >> 1, wn = wave & 1;
    unsigned short* lB0a = &Bs0[(wave * 32) * 32];
    unsigned short* lB0b = &Bs0[(wave * 32 + 16) * 32];
    unsigned short* lB1a = &Bs1[(wave * 32) * 32];
    unsigned short* lB1b = &Bs1[(wave * 32 + 16) * 32];

    for (int nT = 0; nT < 3; nT++) {
        const unsigned short* gB = wpT + (size_t)(nT * 128 + wave * 32 + r_in) * Dm + kc;
        f32x4 acc[2][4];
#pragma unroll
        for (int i = 0; i < 2; i++)
#pragma unroll
            for (int j = 0; j < 4; j++) acc[i][j] = (f32x4){0.f, 0.f, 0.f, 0.f};

        for (int k0 = 0; k0 < Dm; k0 += 64) {
            __syncthreads();
            gl_lds16(gB + k0,            lB0a);
            gl_lds16(gB + 16 * Dm + k0,  lB0b);
            gl_lds16(gB + k0 + 32,       lB1a);
            gl_lds16(gB + 16 * Dm + k0 + 32, lB1b);
            __syncthreads();
            short8 af0[2], af1[2], bf0[4], bf1[4];
#pragma unroll
            for (int i = 0; i < 2; i++) {
                const unsigned short* ar = &Xs[(wm * 32 + i * 16 + l15) * XSS + k0 + quad * 8];
                af0[i] = *(const short8*)ar;
                af1[i] = *(const short8*)(ar + 32);
            }
#pragma unroll
            for (int j = 0; j < 4; j++) {
                bf0[j] = *(const short8*)&Bs0[(wn * 64 + j * 16 + l15) * 32 + quad * 8];
                bf1[j] = *(const short8*)&Bs1[(wn * 64 + j * 16 + l15) * 32 + quad * 8];
            }
#pragma unroll
            for (int i = 0; i < 2; i++)
#pragma unroll
                for (int j = 0; j < 4; j++) {
                    acc[i][j] = __builtin_amdgcn_mfma_f32_16x16x32_bf16(af0[i], bf0[j], acc[i][j], 0, 0, 0);
                    acc[i][j] = __builtin_amdgcn_mfma_f32_16x16x32_bf16(af1[i], bf1[j], acc[i][j], 0, 0, 0);
                }
        }

#pragma unroll
        for (int j = 0; j < 4; j++) {
            int col = nT * 128 + wn * 64 + j * 16 + l15;
            float b = bp[col];
#pragma unroll
            for (int i = 0; i < 2; i++)
#pragma unroll
                for (int r = 0; r < 4; r++) {
                    int lrow = wm * 32 + i * 16 + quad * 4 + r;
                    out[(size_t)rowOut[lrow] + col] = acc[i][j][r] + b;
                }
        }
    }
}

} // namespace

extern "C" void kernel_launch(void* const* d_in, const int* in_sizes, int n_in,
                              void* d_out, int out_size, void* d_ws, size_t ws_size,
                              hipStream_t stream)
{
    const float* x  = (const float*)d_in[0];
    const float* wq = (const float*)d_in[1];
    const float* bq = (const float*)d_in[2];
    const float* wp = (const float*)d_in[3];
    const float* bp = (const float*)d_in[4];
    float* out = (float*)d_out;

    const size_t QK_E  = (size_t)ROWS * QKW;
    const size_t VT_E  = (size_t)Mn * NHn * 48 * 36;
    const size_t ATT_E = (size_t)ROWS * Dm;
    unsigned short* qkb = (unsigned short*)d_ws;
    unsigned short* vt  = qkb + QK_E;
    unsigned short* att = vt + VT_E;      // vt frag-overruns (<=128B) land here: finite bf16, killed by P=0
    unsigned short* wqT = att + ATT_E;
    unsigned short* wpT = wqT + (size_t)K3 * Dm;

    prep_w    <<<(K3 * Dm + Dm * Dm + 255) / 256, 256, 0, stream>>>(wq, wp, wqT, wpT);
    qkv_fused <<<ROWS / 64,       256, 0, stream>>>(x, wqT, bq, qkb, vt);
    attn_mfma <<<(Mn * NHn) / 4,  256, 0, stream>>>(qkb, vt, att);
    proj_fused<<<ROWS / 64,       256, 0, stream>>>(att, wpT, bp, out);
}